// Round 4
// baseline (5881.786 us; speedup 1.0000x reference)
//
#include <hip/hip_runtime.h>

typedef _Float16 half2_t __attribute__((ext_vector_type(2)));
typedef _Float16 f16x8   __attribute__((ext_vector_type(8)));
typedef __bf16   bf16x8  __attribute__((ext_vector_type(8)));
typedef float    f32x4   __attribute__((ext_vector_type(4)));
typedef unsigned short u16x8 __attribute__((ext_vector_type(8)));
typedef unsigned int  uint32;
typedef unsigned long long uint64;

#define LSTM_N 32
#define LSTM_T 2048
#define LSTM_D 256
#define LSTM_H 256
#define NG 1024
#define CH 256                    // time-chunk length
#define NCH (LSTM_T / CH)         // 8 chunks
#define MCH (LSTM_N * CH)         // 8192 c-columns per chunk GEMM

// ---- workspace layout (bytes) ---- (~34.7 MB, proven size in R2/R3)
#define OFF_XG   ((size_t)0)
#define SZ_XG    ((size_t)NG * MCH * 4)             // 33,554,432 xgp[1024 r][8192 c] f32
#define OFF_WIHB (OFF_XG + SZ_XG)
#define SZ_WIHB  ((size_t)NG * LSTM_D * 2)          // w_ih bf16
#define OFF_BIAS (OFF_WIHB + SZ_WIHB)
#define SZ_BIAS  ((size_t)4096)
#define OFF_WPK  (OFF_BIAS + SZ_BIAS)
#define SZ_WPK   ((size_t)2 * 32 * 512 * 16)        // 524,288 w_hh f16 MFMA A-frags
#define OFF_CST  (OFF_WPK + SZ_WPK)
#define SZ_CST   ((size_t)LSTM_N * 256 * 4)         // c state f32
#define OFF_HST  (OFF_CST + SZ_CST)
#define SZ_HST   ((size_t)LSTM_N * 128 * 4)         // h state f16-pairs (u32)
#define OFF_HX   (OFF_HST + SZ_HST)
#define SZ_HX    ((size_t)2 * 2 * 2 * 1024 * 8)     // 65,536 exchange (grp,dir,parity,slot)

__device__ __forceinline__ float sigm(float x) { return 1.f / (1.f + __expf(-x)); }
__device__ __forceinline__ float tanh_fast(float x) { return 2.f / (1.f + __expf(-2.f * x)) - 1.f; }

__device__ __forceinline__ unsigned short f2bf(float f) {
  uint32 u = __builtin_bit_cast(uint32, f);
  uint32 r = (u + 0x7FFFu + ((u >> 16) & 1u)) >> 16;
  return (unsigned short)r;
}

// ---------------- kernels ----------------

__global__ void cvt_bf16_k(const float* __restrict__ src, unsigned short* __restrict__ dst, int n) {
  int i = blockIdx.x * blockDim.x + threadIdx.x;
  if (4 * i + 3 < n) {
    float4 v = ((const float4*)src)[i];
    ushort4 o;
    o.x = f2bf(v.x); o.y = f2bf(v.y); o.z = f2bf(v.z); o.w = f2bf(v.w);
    ((ushort4*)dst)[i] = o;
  }
}

__global__ void bias_sum_k(const float* __restrict__ bih, const float* __restrict__ bhh,
                           float* __restrict__ bias) {
  int g = blockIdx.x * blockDim.x + threadIdx.x;
  if (g < NG) bias[g] = bih[g] + bhh[g];
}

// Pack w_hh f32[1024][256] -> MFMA A-fragments for scan WG p, thread t.
// Wave w of WG p, gate q, k-chunk kc: A-tile rows = q*256 + 128p + 16w + (l&15),
// k = kb(kc) + (l>>4)*8 + 2*rr + {0,1};  kb: kc<4 own half 128p+32kc, else peer.
__global__ void wpack_k(const float* __restrict__ whh, uint32* __restrict__ wpk) {
  int e = blockIdx.x * blockDim.x + threadIdx.x;  // < 131072
  int p = e >> 16;
  int i = (e >> 9) & 127;    // q*32 + kc*4 + rr
  int t = e & 511;
  int q = i >> 5, kc = (i >> 2) & 7, rr = i & 3;
  int w = t >> 6, l = t & 63;
  int grow = q * 256 + 128 * p + 16 * w + (l & 15);
  int kb = (kc < 4) ? (128 * p + 32 * kc) : (128 * (1 - p) + 32 * (kc - 4));
  int k = kb + (l >> 4) * 8 + 2 * rr;
  half2_t h;
  h.x = (_Float16)whh[grow * 256 + k];
  h.y = (_Float16)whh[grow * 256 + k + 1];
  wpk[((p * 32 + q * 8 + kc) * 512 + t) * 4 + rr] = __builtin_bit_cast(uint32, h);
}

// init carried state + zero exchange tags (every launch -> replay-safe)
__global__ void state_init_k(const float* __restrict__ state, float* __restrict__ cst,
                             uint32* __restrict__ hst, uint64* __restrict__ hx) {
  int i = blockIdx.x * blockDim.x + threadIdx.x;  // < 8192
  int n = i >> 8, j = i & 255;
  cst[i] = state[n * 512 + 256 + j];
  if ((j & 1) == 0) {
    half2_t h2;
    h2.x = (_Float16)state[n * 512 + j];
    h2.y = (_Float16)state[n * 512 + j + 1];
    hst[(n << 7) + (j >> 1)] = __builtin_bit_cast(uint32, h2);
  }
  hx[i] = 0ull;
}

// xgp[1024 r][8192 c] = w_ih_bf16[1024x256] @ x^T (+bias per row),
// c = t_loc*32 + n  -> scan reads 16 consecutive samples = 64B per row.
__global__ __launch_bounds__(256) void gemm_xgp(const float* __restrict__ x,
                                                const unsigned short* __restrict__ wb,
                                                const float* __restrict__ bias,
                                                float* __restrict__ xgp, int ch) {
  __shared__ unsigned short As[128 * 40];  // 80B rows (stride 5*16B)
  __shared__ unsigned short Bs[128 * 40];
  const int tid = threadIdx.x;
  const int m0 = blockIdx.y * 128;        // gate-row tile
  const int c0 = blockIdx.x * 128;        // column tile
  const int w = tid >> 6;
  const int lane = tid & 63;
  const int wm = (w >> 1) * 64, wn = (w & 1) * 64;
  const int lr = lane & 15, kg = lane >> 4;
  const int srow = tid >> 1, kh = tid & 1;

  const int cbl = c0 + srow;
  const float* xb = x + (size_t)(cbl & 31) * LSTM_T * LSTM_D
                      + (size_t)(ch * CH + (cbl >> 5)) * LSTM_D + kh * 16;
  const unsigned short* ab = wb + (size_t)(m0 + srow) * 256 + kh * 16;

  f32x4 acc[4][4];
#pragma unroll
  for (int i = 0; i < 4; ++i)
#pragma unroll
    for (int j = 0; j < 4; ++j) acc[i][j] = (f32x4){0.f, 0.f, 0.f, 0.f};

  for (int kt = 0; kt < 8; ++kt) {
    {  // A stage: 16 bf16 from wihb
      uint4 a0 = *(const uint4*)(ab + kt * 32);
      uint4 a1 = *(const uint4*)(ab + kt * 32 + 8);
      *(uint4*)((char*)As + srow * 80 + kh * 32) = a0;
      *(uint4*)((char*)As + srow * 80 + kh * 32 + 16) = a1;
      // B stage: 16 f32 from x, convert to bf16
      const float* bp = xb + kt * 32;
      float4 v0 = *(const float4*)(bp + 0);
      float4 v1 = *(const float4*)(bp + 4);
      float4 v2 = *(const float4*)(bp + 8);
      float4 v3 = *(const float4*)(bp + 12);
      u16x8 o0, o1;
      o0[0] = f2bf(v0.x); o0[1] = f2bf(v0.y); o0[2] = f2bf(v0.z); o0[3] = f2bf(v0.w);
      o0[4] = f2bf(v1.x); o0[5] = f2bf(v1.y); o0[6] = f2bf(v1.z); o0[7] = f2bf(v1.w);
      o1[0] = f2bf(v2.x); o1[1] = f2bf(v2.y); o1[2] = f2bf(v2.z); o1[3] = f2bf(v2.w);
      o1[4] = f2bf(v3.x); o1[5] = f2bf(v3.y); o1[6] = f2bf(v3.z); o1[7] = f2bf(v3.w);
      *(uint4*)((char*)Bs + srow * 80 + kh * 32) = __builtin_bit_cast(uint4, o0);
      *(uint4*)((char*)Bs + srow * 80 + kh * 32 + 16) = __builtin_bit_cast(uint4, o1);
    }
    __syncthreads();
    bf16x8 af[4], bfr[4];
#pragma unroll
    for (int i = 0; i < 4; ++i)
      af[i] = __builtin_bit_cast(bf16x8, *(const uint4*)((char*)As + (wm + 16 * i + lr) * 80 + kg * 16));
#pragma unroll
    for (int j = 0; j < 4; ++j)
      bfr[j] = __builtin_bit_cast(bf16x8, *(const uint4*)((char*)Bs + (wn + 16 * j + lr) * 80 + kg * 16));
#pragma unroll
    for (int i = 0; i < 4; ++i)
#pragma unroll
      for (int j = 0; j < 4; ++j)
        acc[i][j] = __builtin_amdgcn_mfma_f32_16x16x32_bf16(af[i], bfr[j], acc[i][j], 0, 0, 0);
    __syncthreads();
  }
  // epilogue: rows = gate rows (per-row bias), cols = c (16 consecutive per lane group)
  float bias_v[4][4];
#pragma unroll
  for (int i = 0; i < 4; ++i)
#pragma unroll
    for (int r = 0; r < 4; ++r) bias_v[i][r] = bias[m0 + wm + 16 * i + kg * 4 + r];
#pragma unroll
  for (int i = 0; i < 4; ++i)
#pragma unroll
    for (int j = 0; j < 4; ++j)
#pragma unroll
      for (int r = 0; r < 4; ++r)
        xgp[(size_t)(m0 + wm + 16 * i + kg * 4 + r) * MCH + (c0 + wn + 16 * j + lr)]
            = acc[i][j][r] + bias_v[i][r];
}

// Recurrent scan: 4 working WGs = 2 sample-groups x 2 unit-halves.
// grid=16, active blocks (b&7)<2: pairs (b, b+8) share an XCD under round-robin
// (perf only; agent-scope atomics are correct regardless of placement).
// WG (g,p): samples n in [16g,16g+16), units [128p,128p+128) x 4 gates.
// W as MFMA A-frags in 128 regs; gates/cell lane-local; 2 barriers/step.
__global__ __launch_bounds__(512, 2) void lstm_scan(const float* __restrict__ xgp,
                                                    const uint4* __restrict__ wpk4,
                                                    float* __restrict__ cst,
                                                    uint32* __restrict__ hst,
                                                    uint64* __restrict__ hx,
                                                    float* __restrict__ out, int ch) {
  __shared__ uint32 hbuf[16][132];   // [sample][264 f16] row stride 528B (<=2-way banks)
  const int b = blockIdx.x;
  if ((b & 7) >= 2) return;
  const int g = b & 1;
  const int p = b >> 3;
  const int t = threadIdx.x;
  const int w = t >> 6, l = t & 63;
  const int ls = l & 15, lq = l >> 4;

  // W fragments (compiler may use AGPRs; MFMA reads them natively)
  uint4 wfr[32];
#pragma unroll
  for (int i = 0; i < 32; ++i) wfr[i] = wpk4[(p * 32 + i) * 512 + t];

  // full h for this group's 16 samples -> hbuf
  {
    int s = t >> 5, m4 = (t & 31) * 4;
    *(uint4*)&hbuf[s][m4] = *(const uint4*)&hst[(16 * g + s) * 128 + m4];
  }
  const int ubase = 16 * w + 4 * lq;         // unit base within the 128-half
  const int n = 16 * g + ls;                  // sample
  float4 cc4 = *(const float4*)&cst[n * 256 + 128 * p + ubase];
  float cc[4] = {cc4.x, cc4.y, cc4.z, cc4.w};
  __syncthreads();

  const int gsbase = ch * CH;
  uint64* hx_own  = hx + (size_t)(g * 2 + p) * 2048;
  uint64* hx_peer = hx + (size_t)(g * 2 + (1 - p)) * 2048;

  const int rowb = 128 * p + ubase;           // gate-row base (q adds q*256, r adds r)
  const float* xgl = xgp + (size_t)rowb * MCH + n;
  float* outb = out + ((size_t)n * LSTM_T + (size_t)ch * CH) * 256 + 128 * p + ubase;

  const int own_u32 = 64 * p;
  const int peer_u32 = 64 * (1 - p);
  const int slotb = ls * 64 + 8 * w + 2 * lq; // own posting slots (+0,+1)

  float xpre[16];
#pragma unroll
  for (int q = 0; q < 4; ++q)
#pragma unroll
    for (int r = 0; r < 4; ++r)
      xpre[q * 4 + r] = xgl[(size_t)(q * 256 + r) * MCH];

  for (int tt = 0; tt < CH; ++tt) {
    // own-half MFMA (overlaps peer arrival)
    f32x4 acc[4];
#pragma unroll
    for (int q = 0; q < 4; ++q) acc[q] = (f32x4){0.f, 0.f, 0.f, 0.f};
    uint4 bb[4];
#pragma unroll
    for (int kc = 0; kc < 4; ++kc)
      bb[kc] = *(const uint4*)&hbuf[ls][own_u32 + 16 * kc + 4 * lq];
#pragma unroll
    for (int kc = 0; kc < 4; ++kc) {
      f16x8 bv = __builtin_bit_cast(f16x8, bb[kc]);
#pragma unroll
      for (int q = 0; q < 4; ++q)
        acc[q] = __builtin_amdgcn_mfma_f32_16x16x32_f16(
            __builtin_bit_cast(f16x8, wfr[q * 8 + kc]), bv, acc[q], 0, 0, 0);
    }
    // poll peer h-half (tagged u64: data lo32, step tag hi32)
    if (tt > 0) {
      const uint32 gs = (uint32)(gsbase + tt);
      uint64* sp = &hx_peer[(size_t)(gs & 1) * 1024 + 2 * t];
      uint64 v0, v1;
      do {
        v0 = __hip_atomic_load(sp, __ATOMIC_RELAXED, __HIP_MEMORY_SCOPE_AGENT);
      } while ((uint32)(v0 >> 32) != gs);
      do {
        v1 = __hip_atomic_load(sp + 1, __ATOMIC_RELAXED, __HIP_MEMORY_SCOPE_AGENT);
      } while ((uint32)(v1 >> 32) != gs);
      uint2 pv; pv.x = (uint32)v0; pv.y = (uint32)v1;
      *(uint2*)&hbuf[t >> 5][peer_u32 + 2 * (t & 31)] = pv;
    }
    __syncthreads();
    // peer-half MFMA
#pragma unroll
    for (int kc = 0; kc < 4; ++kc)
      bb[kc] = *(const uint4*)&hbuf[ls][peer_u32 + 16 * kc + 4 * lq];
#pragma unroll
    for (int kc = 0; kc < 4; ++kc) {
      f16x8 bv = __builtin_bit_cast(f16x8, bb[kc]);
#pragma unroll
      for (int q = 0; q < 4; ++q)
        acc[q] = __builtin_amdgcn_mfma_f32_16x16x32_f16(
            __builtin_bit_cast(f16x8, wfr[q * 8 + 4 + kc]), bv, acc[q], 0, 0, 0);
    }
    // gates + cell (lane-local: col=sample, row=unit)
    float hv[4];
#pragma unroll
    for (int r = 0; r < 4; ++r) {
      float gi = sigm(acc[0][r] + xpre[0 + r]);
      float gf = sigm(acc[1][r] + xpre[4 + r]);
      float gg = tanh_fast(acc[2][r] + xpre[8 + r]);
      float go = sigm(acc[3][r] + xpre[12 + r]);
      float c2 = gf * cc[r] + gi * gg;
      cc[r] = c2;
      hv[r] = go * tanh_fast(c2);
    }
    half2_t h01, h23;
    h01.x = (_Float16)hv[0]; h01.y = (_Float16)hv[1];
    h23.x = (_Float16)hv[2]; h23.y = (_Float16)hv[3];
    uint32 hu0 = __builtin_bit_cast(uint32, h01);
    uint32 hu1 = __builtin_bit_cast(uint32, h23);
    // post own h-half for peer's next step (immediately, no extra barrier)
    if (tt < CH - 1) {
      const uint32 gs2 = (uint32)(gsbase + tt + 1);
      uint64* dp = &hx_own[(size_t)(gs2 & 1) * 1024 + slotb];
      __hip_atomic_store(dp, (uint64)hu0 | ((uint64)gs2 << 32),
                         __ATOMIC_RELAXED, __HIP_MEMORY_SCOPE_AGENT);
      __hip_atomic_store(dp + 1, (uint64)hu1 | ((uint64)gs2 << 32),
                         __ATOMIC_RELAXED, __HIP_MEMORY_SCOPE_AGENT);
    }
    // own h-half -> LDS for next step's B-frags
    uint2 hw; hw.x = hu0; hw.y = hu1;
    *(uint2*)&hbuf[ls][own_u32 + 8 * w + 2 * lq] = hw;
    // output h (f32), coalesced 64B per 4-lane cluster
    *(float4*)&outb[(size_t)tt * 256] = make_float4(hv[0], hv[1], hv[2], hv[3]);
    if (ch == NCH - 1 && tt == CH - 1) {
      float* os = out + (size_t)LSTM_N * LSTM_T * LSTM_H + n * 512 + 128 * p + ubase;
      *(float4*)os = make_float4(hv[0], hv[1], hv[2], hv[3]);
      *(float4*)(os + 256) = make_float4(cc[0], cc[1], cc[2], cc[3]);
    }
    // prefetch next step's xg (consumed ~1 step later)
    if (tt < CH - 1) {
#pragma unroll
      for (int q = 0; q < 4; ++q)
#pragma unroll
        for (int r = 0; r < 4; ++r)
          xpre[q * 4 + r] = xgl[(size_t)(q * 256 + r) * MCH + (size_t)(tt + 1) * 32];
    }
    __syncthreads();
  }
  // persist carried state for next chunk
  *(float4*)&cst[n * 256 + 128 * p + ubase] = make_float4(cc[0], cc[1], cc[2], cc[3]);
  uint2 hfin = *(uint2*)&hbuf[ls][own_u32 + 8 * w + 2 * lq];
  *(uint2*)&hst[n * 128 + 64 * p + 8 * w + 2 * lq] = hfin;
}

extern "C" void kernel_launch(void* const* d_in, const int* in_sizes, int n_in,
                              void* d_out, int out_size, void* d_ws, size_t ws_size,
                              hipStream_t stream) {
  const float* x   = (const float*)d_in[0];
  const float* st  = (const float*)d_in[1];
  const float* wih = (const float*)d_in[2];
  const float* whh = (const float*)d_in[3];
  const float* bih = (const float*)d_in[4];
  const float* bhh = (const float*)d_in[5];
  float* out = (float*)d_out;
  char* ws = (char*)d_ws;

  float* xgp = (float*)(ws + OFF_XG);
  unsigned short* wihb = (unsigned short*)(ws + OFF_WIHB);
  float* bias = (float*)(ws + OFF_BIAS);
  uint32* wpk = (uint32*)(ws + OFF_WPK);
  float* cst = (float*)(ws + OFF_CST);
  uint32* hst = (uint32*)(ws + OFF_HST);
  uint64* hx = (uint64*)(ws + OFF_HX);

  cvt_bf16_k<<<(NG * LSTM_D / 4 + 255) / 256, 256, 0, stream>>>(wih, wihb, NG * LSTM_D);
  bias_sum_k<<<4, 256, 0, stream>>>(bih, bhh, bias);
  wpack_k<<<512, 256, 0, stream>>>(whh, wpk);
  state_init_k<<<32, 256, 0, stream>>>(st, cst, hst, hx);

  for (int ch = 0; ch < NCH; ++ch) {
    gemm_xgp<<<dim3(MCH / 128, NG / 128), 256, 0, stream>>>(x, wihb, bias, xgp, ch);
    lstm_scan<<<16, 512, 0, stream>>>(xgp, (const uint4*)wpk, cst, hst, hx, out, ch);
  }
}

// Round 6
// 4887.992 us; speedup vs baseline: 1.2033x; 1.2033x over previous
//
#include <hip/hip_runtime.h>

typedef _Float16 half2_t __attribute__((ext_vector_type(2)));
typedef __bf16   bf16x8  __attribute__((ext_vector_type(8)));
typedef float    f32x4   __attribute__((ext_vector_type(4)));
typedef unsigned short u16x8 __attribute__((ext_vector_type(8)));
typedef unsigned int  uint32;
typedef unsigned long long uint64;

#define LSTM_N 32
#define LSTM_T 2048
#define LSTM_D 256
#define LSTM_H 256
#define NG 1024
#define CH 256                    // time-chunk length
#define NCH (LSTM_T / CH)         // 8 chunks
#define MCH (LSTM_N * CH)         // 8192 rows per chunk GEMM

// ---- workspace layout (bytes) ---- (~34.7 MB, proven safe R2-R5)
#define OFF_XG   ((size_t)0)
#define SZ_XG    ((size_t)MCH * NG * 4)             // 33,554,432 xg chunk f32
#define OFF_WIHB (OFF_XG + SZ_XG)
#define SZ_WIHB  ((size_t)NG * LSTM_D * 2)          // w_ih bf16
#define OFF_BIAS (OFF_WIHB + SZ_WIHB)
#define SZ_BIAS  ((size_t)4096)
#define OFF_WPK  (OFF_BIAS + SZ_BIAS)
#define SZ_WPK   ((size_t)2 * 32 * 512 * 16)        // 524,288 w_hh f16 pairs (per-WG layout)
#define OFF_CST  (OFF_WPK + SZ_WPK)
#define SZ_CST   ((size_t)LSTM_N * 256 * 4)         // c state f32
#define OFF_HST  (OFF_CST + SZ_CST)
#define SZ_HST   ((size_t)LSTM_N * 128 * 4)         // h state f16-pairs (u32)
#define OFF_HX   (OFF_HST + SZ_HST)
#define SZ_HX    ((size_t)LSTM_N * 2 * 2 * 64 * 8)  // 65,536 tagged-u64 exchange slots

#if defined(__has_builtin)
#if __has_builtin(__builtin_amdgcn_fdot2)
#define HAVE_FDOT2 1
#endif
#endif

__device__ __forceinline__ float fdot2(uint32 w, uint32 h, float acc) {
#ifdef HAVE_FDOT2
  return __builtin_amdgcn_fdot2(__builtin_bit_cast(half2_t, w),
                                __builtin_bit_cast(half2_t, h), acc, false);
#else
  half2_t wv = __builtin_bit_cast(half2_t, w);
  half2_t hv = __builtin_bit_cast(half2_t, h);
  float r = fmaf((float)wv.x, (float)hv.x, acc);
  return fmaf((float)wv.y, (float)hv.y, r);
#endif
}

__device__ __forceinline__ float sigm(float x) { return 1.f / (1.f + __expf(-x)); }
__device__ __forceinline__ float tanh_fast(float x) { return 2.f / (1.f + __expf(-2.f * x)) - 1.f; }

__device__ __forceinline__ unsigned short f2bf(float f) {
  uint32 u = __builtin_bit_cast(uint32, f);
  uint32 r = (u + 0x7FFFu + ((u >> 16) & 1u)) >> 16;
  return (unsigned short)r;
}

// reduce-scatter over 8 kappa-lanes: lane kap ends with full sum of a[kap].
// Compile-time register indices only (rule #20). Proven R2/R3.
__device__ __forceinline__ float bfly8(const float a[8], int kap) {
  float k0[4], g0[4];
  const bool b4 = (kap & 4) != 0;
#pragma unroll
  for (int v = 0; v < 4; ++v) {
    k0[v] = b4 ? a[v + 4] : a[v];
    g0[v] = b4 ? a[v] : a[v + 4];
  }
#pragma unroll
  for (int v = 0; v < 4; ++v) k0[v] += __shfl_xor(g0[v], 4, 64);
  float k1[2], g1[2];
  const bool b2 = (kap & 2) != 0;
#pragma unroll
  for (int v = 0; v < 2; ++v) {
    k1[v] = b2 ? k0[v + 2] : k0[v];
    g1[v] = b2 ? k0[v] : k0[v + 2];
  }
#pragma unroll
  for (int v = 0; v < 2; ++v) k1[v] += __shfl_xor(g1[v], 2, 64);
  const bool b1 = (kap & 1) != 0;
  float k2 = b1 ? k1[1] : k1[0];
  float g2 = b1 ? k1[0] : k1[1];
  return k2 + __shfl_xor(g2, 1, 64);
}

// ---------------- kernels (cvt/bias/wpack/state_init/gemm = R3 verbatim) ----------------

__global__ void cvt_bf16_k(const float* __restrict__ src, unsigned short* __restrict__ dst, int n) {
  int i = blockIdx.x * blockDim.x + threadIdx.x;
  if (4 * i + 3 < n) {
    float4 v = ((const float4*)src)[i];
    ushort4 o;
    o.x = f2bf(v.x); o.y = f2bf(v.y); o.z = f2bf(v.z); o.w = f2bf(v.w);
    ((ushort4*)dst)[i] = o;
  }
}

__global__ void bias_sum_k(const float* __restrict__ bih, const float* __restrict__ bhh,
                           float* __restrict__ bias) {
  int g = blockIdx.x * blockDim.x + threadIdx.x;
  if (g < NG) bias[g] = bih[g] + bhh[g];
}

// Pack w_hh f32[1024][256] -> per-(WG p, thread t) f16-pair reg images.
// Scan WG p owns gate rows {q*256 + 128p + u}; thread t: kap=t&7, rg=t>>3,
// local rows lr=8rg+rho (rho 0..7, q=lr>>7, u=lr&127); k-slice: j<8 own half
// (k=128p+16kap+2j), j>=8 peer half (k=128(1-p)+16kap+2(j-8)).   [R3 verbatim]
__global__ void wpack_k(const float* __restrict__ whh, uint32* __restrict__ wpk) {
  int e = blockIdx.x * blockDim.x + threadIdx.x;  // < 131072
  int p = e >> 16;
  int rem = e & 0xFFFF;
  int i = rem >> 9;        // 0..127
  int t = rem & 511;
  int rho = i >> 4, j = i & 15;
  int kap = t & 7, rg = t >> 3;
  int lr = 8 * rg + rho;
  int q = lr >> 7, u = lr & 127;
  int r = q * 256 + 128 * p + u;
  int k = (j < 8) ? (128 * p + 16 * kap + 2 * j)
                  : (128 * (1 - p) + 16 * kap + 2 * (j - 8));
  half2_t h;
  h.x = (_Float16)whh[r * 256 + k];
  h.y = (_Float16)whh[r * 256 + k + 1];
  wpk[((p * 32 + (i >> 2)) * 512 + t) * 4 + (i & 3)] = __builtin_bit_cast(uint32, h);
}

// init carried state + zero exchange tags (every launch -> replay-safe) [R3 verbatim]
__global__ void state_init_k(const float* __restrict__ state, float* __restrict__ cst,
                             uint32* __restrict__ hst, uint64* __restrict__ hx) {
  int i = blockIdx.x * blockDim.x + threadIdx.x;  // < 8192
  int n = i >> 8, j = i & 255;
  cst[i] = state[n * 512 + 256 + j];
  if ((j & 1) == 0) {
    half2_t h2;
    h2.x = (_Float16)state[n * 512 + j];
    h2.y = (_Float16)state[n * 512 + j + 1];
    hst[(n << 7) + (j >> 1)] = __builtin_bit_cast(uint32, h2);
  }
  hx[i] = 0ull;
}

// xg[8192][1024] = x(chunk rows, cvt bf16 inline) @ w_ih_bf16^T + bias  [R2/R3 verbatim]
__global__ __launch_bounds__(256) void gemm_xg(const float* __restrict__ x,
                                               const unsigned short* __restrict__ wb,
                                               const float* __restrict__ bias,
                                               float* __restrict__ xg, int ch) {
  __shared__ unsigned short As[128 * 40];  // 80B rows (stride = 5*16B, odd*16)
  __shared__ unsigned short Bs[128 * 40];
  const int tid = threadIdx.x;
  const int m0 = blockIdx.y * 128;
  const int g0 = blockIdx.x * 128;
  const int w = tid >> 6;
  const int lane = tid & 63;
  const int wm = (w >> 1) * 64, wn = (w & 1) * 64;
  const int row_l = tid >> 2;  // 0..63
  const int q = tid & 3;
  const int lr = lane & 15, kg = lane >> 4;

  size_t grow[2];
#pragma unroll
  for (int r = 0; r < 2; ++r) {
    int gm = m0 + row_l + 64 * r;
    grow[r] = (size_t)(gm >> 8) * LSTM_T + (size_t)ch * CH + (gm & 255);
  }

  f32x4 acc[4][4];
#pragma unroll
  for (int i = 0; i < 4; ++i)
#pragma unroll
    for (int j = 0; j < 4; ++j) acc[i][j] = (f32x4){0.f, 0.f, 0.f, 0.f};

  for (int kt = 0; kt < 8; ++kt) {
#pragma unroll
    for (int r = 0; r < 2; ++r) {
      int row = row_l + 64 * r;
      const float* ap = x + grow[r] * 256 + kt * 32 + q * 8;
      float4 v0 = *(const float4*)ap;
      float4 v1 = *(const float4*)(ap + 4);
      u16x8 o;
      o[0] = f2bf(v0.x); o[1] = f2bf(v0.y); o[2] = f2bf(v0.z); o[3] = f2bf(v0.w);
      o[4] = f2bf(v1.x); o[5] = f2bf(v1.y); o[6] = f2bf(v1.z); o[7] = f2bf(v1.w);
      *(uint4*)((char*)As + row * 80 + q * 16) = __builtin_bit_cast(uint4, o);
      uint4 bv = *(const uint4*)(wb + (size_t)(g0 + row) * 256 + kt * 32 + q * 8);
      *(uint4*)((char*)Bs + row * 80 + q * 16) = bv;
    }
    __syncthreads();
    bf16x8 af[4], bfr[4];
#pragma unroll
    for (int i = 0; i < 4; ++i)
      af[i] = __builtin_bit_cast(bf16x8, *(const uint4*)((char*)As + (wm + 16 * i + lr) * 80 + kg * 16));
#pragma unroll
    for (int j = 0; j < 4; ++j)
      bfr[j] = __builtin_bit_cast(bf16x8, *(const uint4*)((char*)Bs + (wn + 16 * j + lr) * 80 + kg * 16));
#pragma unroll
    for (int i = 0; i < 4; ++i)
#pragma unroll
      for (int j = 0; j < 4; ++j)
        acc[i][j] = __builtin_amdgcn_mfma_f32_16x16x32_bf16(af[i], bfr[j], acc[i][j], 0, 0, 0);
    __syncthreads();
  }
#pragma unroll
  for (int j = 0; j < 4; ++j) {
    int gc = g0 + wn + 16 * j + lr;
    float bj = bias[gc];
#pragma unroll
    for (int i = 0; i < 4; ++i) {
#pragma unroll
      for (int r = 0; r < 4; ++r) {
        int m = m0 + wm + 16 * i + kg * 4 + r;
        xg[(size_t)m * NG + gc] = acc[i][j][r] + bj;
      }
    }
  }
}

// Recurrent scan: R3 datapath (mapping/numerics identical) with latency cuts:
// per-thread register poll (no LDS hop, no poll barrier), parity-dbuf own-h,
// 2 barriers/step, full-register budget (occupancy moot: 64 WGs / 256 CUs).
// Thread t: kap=t&7 (k-slice), rg=t>>3 (rows 8rg..8rg+7); finalizes lr=t,
// gate q=t>>7, unit u=t&127, row R=q*256+128p+u.
__global__ __launch_bounds__(512, 1) void lstm_scan(const float* __restrict__ xg,
                                                    const uint4* __restrict__ wpk4,
                                                    float* __restrict__ cst,
                                                    uint32* __restrict__ hst,
                                                    uint64* __restrict__ hx,
                                                    float* __restrict__ out, int ch) {
  __shared__ float actb[512];
  __shared__ uint32 hown[2][64];   // own-half h f16-pairs, parity per step

  const int b = blockIdx.x;
  const int n = b & 31;
  const int p = b >> 5;
  const int t = threadIdx.x;
  const int kap = t & 7;
  const int q = t >> 7;                 // wave-uniform gate: 0=i 1=f 2=g 3=o
  const int u = t & 127;
  const int R = q * 256 + 128 * p + u;  // finalized gate row

  // weights -> 128 regs (R3-verbatim load)
  uint32 wr[128];
#pragma unroll
  for (int ig = 0; ig < 32; ++ig) {
    uint4 v = wpk4[(p * 32 + ig) * 512 + t];
    wr[4 * ig + 0] = v.x; wr[4 * ig + 1] = v.y; wr[4 * ig + 2] = v.z; wr[4 * ig + 3] = v.w;
  }
  float c = 0.f;
  if (t < 128) c = cst[n * 256 + 128 * p + t];
  if (t < 64) hown[0][t] = hst[n * 128 + 64 * p + t];
  __syncthreads();

  const float* xgn = xg + (size_t)n * CH * NG;
  float* outb = out + ((size_t)n * LSTM_T + (size_t)ch * CH) * LSTM_H;
  uint64* hx_own  = hx + (size_t)(n * 2 + p) * 128;
  uint64* hx_peer = hx + (size_t)(n * 2 + (1 - p)) * 128;
  const int gsbase = ch * CH;

  float xcur = xgn[R];

  for (int tt = 0; tt < CH; ++tt) {
    const uint32 gs = (uint32)(gsbase + tt);
    // peer h-slice: chunk-start from hst (R3's proven path), else tagged slots
    uint64 pv[8];
    uint32 hrp[8];
    if (tt == 0) {
#pragma unroll
      for (int m = 0; m < 8; ++m) hrp[m] = hst[n * 128 + 64 * (1 - p) + 8 * kap + m];
    } else {
      uint64* sp = &hx_peer[(size_t)(gs & 1) * 64 + 8 * kap];
#pragma unroll
      for (int ss = 0; ss < 8; ++ss)
        pv[ss] = __hip_atomic_load(&sp[ss], __ATOMIC_RELAXED, __HIP_MEMORY_SCOPE_AGENT);
    }
    // xg prefetch for next step (hidden under dots)
    float xnext = (tt < CH - 1) ? xgn[(size_t)(tt + 1) * NG + R] : 0.f;
    // own h-slice (broadcast LDS reads, parity buffer)
    uint32 hro[8];
    *(uint4*)&hro[0] = *(const uint4*)&hown[tt & 1][8 * kap];
    *(uint4*)&hro[4] = *(const uint4*)&hown[tt & 1][8 * kap + 4];
    // own-half partial dots: 8 rows x 8 fdot2 (R3 order)
    float acc[8];
#pragma unroll
    for (int j = 0; j < 8; ++j) {
      float a = 0.f;
#pragma unroll
      for (int m = 0; m < 8; ++m) a = fdot2(wr[j * 16 + m], hro[m], a);
      acc[j] = a;
    }
    if (tt > 0) {  // verify tags; reload-all until every slot matches
      bool ok;
      do {
        ok = true;
#pragma unroll
        for (int ss = 0; ss < 8; ++ss) ok &= ((uint32)(pv[ss] >> 32) == gs);
        if (!ok) {
          uint64* sp = &hx_peer[(size_t)(gs & 1) * 64 + 8 * kap];
#pragma unroll
          for (int ss = 0; ss < 8; ++ss)
            pv[ss] = __hip_atomic_load(&sp[ss], __ATOMIC_RELAXED, __HIP_MEMORY_SCOPE_AGENT);
        }
      } while (!ok);
#pragma unroll
      for (int ss = 0; ss < 8; ++ss) hrp[ss] = (uint32)pv[ss];
    }
    // peer-half partial dots (R3 order)
#pragma unroll
    for (int j = 0; j < 8; ++j) {
      float a = acc[j];
#pragma unroll
      for (int m = 0; m < 8; ++m) a = fdot2(wr[j * 16 + 8 + m], hrp[m], a);
      acc[j] = a;
    }
    float s = bfly8(acc, kap);
    float pre = s + xcur;
    xcur = xnext;
    float a0 = (q == 2) ? tanh_fast(pre) : sigm(pre);
    actb[t] = a0;
    __syncthreads();                        // BAR-A: gates ready (and all polls consumed)
    if (t < 128) {                          // cell update: unit t of own half
      float gi = actb[t];
      float gf = actb[128 + t];
      float gg = actb[256 + t];
      float go = actb[384 + t];
      c = gf * c + gi * gg;
      float h = go * tanh_fast(c);
      _Float16 hf = (_Float16)h;
      unsigned short hu = __builtin_bit_cast(unsigned short, hf);
      ((unsigned short*)&hown[(tt + 1) & 1][0])[t] = hu;   // next-step own half
      outb[(size_t)tt * LSTM_H + 128 * p + t] = h;
      uint32 hz = (uint32)hu;
      uint32 hn = (uint32)__shfl_xor((int)hz, 1, 64);      // partner unit t^1
      if (tt < CH - 1 && (t & 1) == 0) {    // post pair (t, t+1) for peer's next step
        const uint32 gs2 = gs + 1;
        uint64 msg = (uint64)(hz | (hn << 16)) | ((uint64)gs2 << 32);
        __hip_atomic_store(&hx_own[(size_t)(gs2 & 1) * 64 + (t >> 1)], msg,
                           __ATOMIC_RELAXED, __HIP_MEMORY_SCOPE_AGENT);
      }
      if (ch == NCH - 1 && tt == CH - 1) {
        float* os = out + (size_t)LSTM_N * LSTM_T * LSTM_H + n * 512;
        os[128 * p + t] = h;
        os[256 + 128 * p + t] = c;
      }
    }
    __syncthreads();                        // BAR-B: hown[(tt+1)&1] visible
  }
  // persist carried state (CH even -> final h landed in hown[0])
  if (t < 128) cst[n * 256 + 128 * p + t] = c;
  if (t < 64) hst[n * 128 + 64 * p + t] = hown[0][t];
}

extern "C" void kernel_launch(void* const* d_in, const int* in_sizes, int n_in,
                              void* d_out, int out_size, void* d_ws, size_t ws_size,
                              hipStream_t stream) {
  const float* x   = (const float*)d_in[0];
  const float* st  = (const float*)d_in[1];
  const float* wih = (const float*)d_in[2];
  const float* whh = (const float*)d_in[3];
  const float* bih = (const float*)d_in[4];
  const float* bhh = (const float*)d_in[5];
  float* out = (float*)d_out;
  char* ws = (char*)d_ws;

  float* xg = (float*)(ws + OFF_XG);
  unsigned short* wihb = (unsigned short*)(ws + OFF_WIHB);
  float* bias = (float*)(ws + OFF_BIAS);
  uint32* wpk = (uint32*)(ws + OFF_WPK);
  float* cst = (float*)(ws + OFF_CST);
  uint32* hst = (uint32*)(ws + OFF_HST);
  uint64* hx = (uint64*)(ws + OFF_HX);

  cvt_bf16_k<<<(NG * LSTM_D / 4 + 255) / 256, 256, 0, stream>>>(wih, wihb, NG * LSTM_D);
  bias_sum_k<<<4, 256, 0, stream>>>(bih, bhh, bias);
  wpack_k<<<512, 256, 0, stream>>>(whh, wpk);
  state_init_k<<<32, 256, 0, stream>>>(st, cst, hst, hx);

  for (int ch = 0; ch < NCH; ++ch) {
    gemm_xg<<<dim3(NG / 128, MCH / 128), 256, 0, stream>>>(x, wihb, bias, xg, ch);
    lstm_scan<<<64, 512, 0, stream>>>(xg, (const uint4*)wpk, cst, hst, hx, out, ch);
  }
}